// Round 5
// baseline (78.527 us; speedup 1.0000x reference)
//
#include <hip/hip_runtime.h>
#include <math.h>
#include <float.h>

#define B_ 64
#define T_ 100
#define N_ 20000
#define NQ (B_ * T_)              // 6400 queries
#define QG 256                    // queries per group = one block (4 per lane)
#define NQG (NQ / QG)             // 25 query groups
#define PTB 800                   // points per block (4 waves x 200)
#define PPB (PTB / 2)             // 400 point-pairs per block
#define BPQ (N_ / PTB)            // 25 point-slices = blocks per query group
#define GPW20 10                  // groups of 20 points (10 pairs) per wave
#define EPI_T 64                  // k_epilogue block size (grid 100)

typedef float f2 __attribute__((ext_vector_type(2)));
typedef float f4 __attribute__((ext_vector_type(4)));
typedef unsigned long long u64;

// ws layout: u64 partial[BPQ][NQ]  (25 * 6400 * 8 = 1.28 MB)
// Every slot is written by its owning block -> no init pass, no atomics.
#define PART_OFF 0

// Map f32 -> u32 preserving < order for all finite values (incl. negatives).
__device__ __forceinline__ unsigned int f32_sortable(float f) {
    unsigned int u = __float_as_uint(f);
    return ((int)u >= 0) ? (u | 0x80000000u) : ~u;
}

// e = p2 - 2 q.g for a point-PAIR, FMA nesting identical to the verified
// kernels: fma(mx, qx, fma(my, qy, fma(mz, qz, p2)))
__device__ __forceinline__ f2 edist2(f4 A, f4 Bv, f2 vx, f2 vy, f2 vz) {
    f2 mx = { A.x,  A.y  }, my = { A.z,  A.w  };
    f2 mz = { Bv.x, Bv.y }, p2 = { Bv.z, Bv.w };
    return __builtin_elementwise_fma(mx, vx,
           __builtin_elementwise_fma(my, vy,
           __builtin_elementwise_fma(mz, vz, p2)));
}

// min of 3 — nested minnum, fusible to v_min3_f32 (exact for finite f32;
// reduction-order change cannot alter the min VALUE, so results stay
// bit-identical and the equality-resolve below is unaffected).
__device__ __forceinline__ float min3f(float a, float b, float c) {
    return fminf(fminf(a, b), c);
}

// ---------------------------------------------------------------------------
// Kernel 1: NN. Block = (query-group of 256, point-slice of 800).
// Rigid transforms preserve distance, so the search runs in the global
// frame: q = R w + t, e = |g|^2 - 2 q.g (argmin-equivalent to |q-g|^2).
// Query sharing: each THREAD computes one query (bit-identical expression),
// publishes via SoA LDS; each LANE then owns 4 queries as hoisted splats.
// Each WAVE covers all 256 queries x its 200-point sub-slice via uniform
// (broadcast, conflict-free) LDS reads. Argmin tracked per 20-point group
// (10 groups/wave, exact fit): 30 pk-FMA + ~10 min3-tree + 3 bookkeeping
// per 40 pairs; exact index resolved afterwards with identical FMA math +
// lowest-index tie-break. 4 waves' keys min-reduce through LDS, one u64
// per query to partial[slice][query]. No atomics, no init kernel.
// ---------------------------------------------------------------------------
__global__ __launch_bounds__(256, 3) void k_nn(
    const float* __restrict__ poses,      // [B,4,4]
    const float* __restrict__ wpts,       // [B,T,3]
    const float* __restrict__ boundary,   // [4,N]
    u64* __restrict__ partial,            // [BPQ][NQ]
    float* __restrict__ out)
{
    __shared__ f4 sh[PPB][2];             // pair-packed points, 12.8 KB
    __shared__ float qsh[3][QG];          // SoA queries, 3 KB
    __shared__ u64 red[4 * 256];          // cross-wave key reduce, 8 KB

    const int bx   = blockIdx.x;
    const int qg   = bx / BPQ;
    const int bsl  = bx - qg * BPQ;
    const int tid  = threadIdx.x;
    const int lane = tid & 63;
    const int wv   = tid >> 6;
    const int pbase = bsl * PTB;

    // out is consumed by k_epilogue (next dispatch) via atomicAdd; zero here.
    if (bx == 0 && tid == 0) out[0] = 0.0f;

    // ---- stage slice: (-2g, |g|^2) pair-packed (identical arithmetic) ----
    for (int pp = tid; pp < PPB; pp += 256) {
        const int n0 = pbase + 2 * pp;
        const f2 xx = *(const f2*)&boundary[n0];
        const f2 yy = *(const f2*)&boundary[N_ + n0];
        const f2 zz = *(const f2*)&boundary[2 * N_ + n0];
        const float x0 = xx.x, x1 = xx.y;
        const float y0 = yy.x, y1 = yy.y;
        const float z0 = zz.x, z1 = zz.y;
        f4 a = { -2.f * x0, -2.f * x1, -2.f * y0, -2.f * y1 };
        f4 b = { -2.f * z0, -2.f * z1,
                 x0 * x0 + y0 * y0 + z0 * z0,
                 x1 * x1 + y1 * y1 + z1 * z1 };
        sh[pp][0] = a;
        sh[pp][1] = b;
    }

    // ---- one query per thread: global waypoint q = R w + t -> LDS ----
    {
        const int i = qg * QG + tid;
        const int b = i / T_;
        const float* P = poses + b * 16;
        const float* W = wpts + i * 3;
        const float wx = W[0], wy = W[1], wz = W[2];
        qsh[0][tid] = P[0] * wx + P[1] * wy + P[2]  * wz + P[3];
        qsh[1][tid] = P[4] * wx + P[5] * wy + P[6]  * wz + P[7];
        qsh[2][tid] = P[8] * wx + P[9] * wy + P[10] * wz + P[11];
    }
    __syncthreads();

    // ---- 4 queries per lane, splats hoisted ----
    f2 vx[4], vy[4], vz[4];
#pragma unroll
    for (int s = 0; s < 4; ++s) {
        const int qi = s * 64 + lane;
        const float qxx = qsh[0][qi];
        const float qyy = qsh[1][qi];
        const float qzz = qsh[2][qi];
        vx[s] = (f2){ qxx, qxx };
        vy[s] = (f2){ qyy, qyy };
        vz[s] = (f2){ qzz, qzz };
    }

    const int prbase = wv * (PPB / 4);    // wave's pair base (wv*100)

    float best[4] = { FLT_MAX, FLT_MAX, FLT_MAX, FLT_MAX };
    int   bg[4]   = { 0, 0, 0, 0 };

#pragma unroll 2
    for (int g = 0; g < GPW20; ++g) {
        const int pr = prbase + 10 * g;
        const f4 A0 = sh[pr][0],     B0 = sh[pr][1];
        const f4 A1 = sh[pr + 1][0], B1 = sh[pr + 1][1];
        const f4 A2 = sh[pr + 2][0], B2 = sh[pr + 2][1];
        const f4 A3 = sh[pr + 3][0], B3 = sh[pr + 3][1];
        const f4 A4 = sh[pr + 4][0], B4 = sh[pr + 4][1];
        const f4 A5 = sh[pr + 5][0], B5 = sh[pr + 5][1];
        const f4 A6 = sh[pr + 6][0], B6 = sh[pr + 6][1];
        const f4 A7 = sh[pr + 7][0], B7 = sh[pr + 7][1];
        const f4 A8 = sh[pr + 8][0], B8 = sh[pr + 8][1];
        const f4 A9 = sh[pr + 9][0], B9 = sh[pr + 9][1];
#pragma unroll
        for (int s = 0; s < 4; ++s) {
            const f2 e0 = edist2(A0, B0, vx[s], vy[s], vz[s]);
            const f2 e1 = edist2(A1, B1, vx[s], vy[s], vz[s]);
            const f2 e2 = edist2(A2, B2, vx[s], vy[s], vz[s]);
            const f2 e3 = edist2(A3, B3, vx[s], vy[s], vz[s]);
            const f2 e4 = edist2(A4, B4, vx[s], vy[s], vz[s]);
            const f2 e5 = edist2(A5, B5, vx[s], vy[s], vz[s]);
            const f2 e6 = edist2(A6, B6, vx[s], vy[s], vz[s]);
            const f2 e7 = edist2(A7, B7, vx[s], vy[s], vz[s]);
            const f2 e8 = edist2(A8, B8, vx[s], vy[s], vz[s]);
            const f2 e9 = edist2(A9, B9, vx[s], vy[s], vz[s]);
            const float t0 = min3f(e0.x, e0.y, e1.x);
            const float t1 = min3f(e1.y, e2.x, e2.y);
            const float t2 = min3f(e3.x, e3.y, e4.x);
            const float t3 = min3f(e4.y, e5.x, e5.y);
            const float t4 = min3f(e6.x, e6.y, e7.x);
            const float t5 = min3f(e7.y, e8.x, e8.y);
            const float t6 = min3f(e9.x, e9.y, t0);
            const float t7 = min3f(t1, t2, t3);
            const float t8 = min3f(t4, t5, t6);
            const float sc = fminf(t7, t8);
            bg[s]   = (sc < best[s]) ? g : bg[s];
            best[s] = fminf(sc, best[s]);
        }
    }

    // ---- resolve exact index inside winning 20-group (identical FMA math) -
#pragma unroll
    for (int s = 0; s < 4; ++s) {
        const int pr = prbase + 10 * bg[s];
        const f4 A0 = sh[pr][0],     B0 = sh[pr][1];
        const f4 A1 = sh[pr + 1][0], B1 = sh[pr + 1][1];
        const f4 A2 = sh[pr + 2][0], B2 = sh[pr + 2][1];
        const f4 A3 = sh[pr + 3][0], B3 = sh[pr + 3][1];
        const f4 A4 = sh[pr + 4][0], B4 = sh[pr + 4][1];
        const f4 A5 = sh[pr + 5][0], B5 = sh[pr + 5][1];
        const f4 A6 = sh[pr + 6][0], B6 = sh[pr + 6][1];
        const f4 A7 = sh[pr + 7][0], B7 = sh[pr + 7][1];
        const f4 A8 = sh[pr + 8][0], B8 = sh[pr + 8][1];
        const f4 A9 = sh[pr + 9][0], B9 = sh[pr + 9][1];
        const f2 e0 = edist2(A0, B0, vx[s], vy[s], vz[s]);
        const f2 e1 = edist2(A1, B1, vx[s], vy[s], vz[s]);
        const f2 e2 = edist2(A2, B2, vx[s], vy[s], vz[s]);
        const f2 e3 = edist2(A3, B3, vx[s], vy[s], vz[s]);
        const f2 e4 = edist2(A4, B4, vx[s], vy[s], vz[s]);
        const f2 e5 = edist2(A5, B5, vx[s], vy[s], vz[s]);
        const f2 e6 = edist2(A6, B6, vx[s], vy[s], vz[s]);
        const f2 e7 = edist2(A7, B7, vx[s], vy[s], vz[s]);
        const f2 e8 = edist2(A8, B8, vx[s], vy[s], vz[s]);
        const f2 e9 = edist2(A9, B9, vx[s], vy[s], vz[s]);
        const int base_i = pbase + wv * 200 + 20 * bg[s];
        const float bv = best[s];
        const int li = (e0.x == bv) ? base_i
                     : (e0.y == bv) ? base_i + 1
                     : (e1.x == bv) ? base_i + 2
                     : (e1.y == bv) ? base_i + 3
                     : (e2.x == bv) ? base_i + 4
                     : (e2.y == bv) ? base_i + 5
                     : (e3.x == bv) ? base_i + 6
                     : (e3.y == bv) ? base_i + 7
                     : (e4.x == bv) ? base_i + 8
                     : (e4.y == bv) ? base_i + 9
                     : (e5.x == bv) ? base_i + 10
                     : (e5.y == bv) ? base_i + 11
                     : (e6.x == bv) ? base_i + 12
                     : (e6.y == bv) ? base_i + 13
                     : (e7.x == bv) ? base_i + 14
                     : (e7.y == bv) ? base_i + 15
                     : (e8.x == bv) ? base_i + 16
                     : (e8.y == bv) ? base_i + 17
                     : (e9.x == bv) ? base_i + 18 : base_i + 19;
        red[wv * 256 + s * 64 + lane] =
            ((u64)f32_sortable(bv) << 32) | (unsigned)li;
    }
    __syncthreads();

    // ---- cross-wave min (4 slices of the block) -> one u64 per query ----
    {
        const u64 a = red[tid],       b = red[256 + tid];
        const u64 c = red[512 + tid], d = red[768 + tid];
        const u64 m0 = a < b ? a : b;
        const u64 m1 = c < d ? c : d;
        partial[bsl * NQ + qg * QG + tid] = m0 < m1 ? m0 : m1;
    }
}

// ---------------------------------------------------------------------------
// Kernel 2: per query, min over the 25 slice-partials (coalesced), unpack
// winning index, global-frame epilogue: dots = (q - g) . n (rotation-
// invariant == reference's local-frame dot), ExpRelu, block-reduce, atomicAdd.
// Grid 100 x 64 for wide CU coverage on the latency-sensitive gather.
// ---------------------------------------------------------------------------
__global__ __launch_bounds__(EPI_T) void k_epilogue(
    const float* __restrict__ poses,
    const float* __restrict__ wpts,
    const float* __restrict__ boundary,   // [4,N]
    const float* __restrict__ bnorm,      // [3,N]
    const u64* __restrict__ partial,
    float* __restrict__ out)
{
    const int tid = threadIdx.x;
    const int i = blockIdx.x * EPI_T + tid;   // grid = 100 -> i in [0,6400)

    u64 best = ~0ull;
#pragma unroll
    for (int sl = 0; sl < BPQ; ++sl) {
        const u64 k = partial[sl * NQ + i];
        best = k < best ? k : best;
    }
    const int bi = (int)(unsigned)(best & 0xFFFFFFFFull);

    const int b = i / T_;
    const float* P = poses + b * 16;
    const float* W = wpts + i * 3;
    const float wx = W[0], wy = W[1], wz = W[2];
    const float qx = P[0] * wx + P[1] * wy + P[2]  * wz + P[3];
    const float qy = P[4] * wx + P[5] * wy + P[6]  * wz + P[7];
    const float qz = P[8] * wx + P[9] * wy + P[10] * wz + P[11];

    const float gx = boundary[bi], gy = boundary[N_ + bi], gz = boundary[2 * N_ + bi];
    const float nx = bnorm[bi],    ny = bnorm[N_ + bi],    nz = bnorm[2 * N_ + bi];

    const float dots = (qx - gx) * nx + (qy - gy) * ny + (qz - gz) * nz;
    // ExpRelu: alpha=1, beta=0.5; pre-scaled for the final mean
    float val = (dots > 0.0f) ? (dots + 1.0f) : expf(0.5f * dots);
    val *= (1.0f / (float)NQ);

    __shared__ float redf[EPI_T];
    redf[tid] = val;
    __syncthreads();
#pragma unroll
    for (int s = EPI_T / 2; s > 0; s >>= 1) {
        if (tid < s) redf[tid] += redf[tid + s];
        __syncthreads();
    }
    if (tid == 0) atomicAdd(out, redf[0]);
}

extern "C" void kernel_launch(void* const* d_in, const int* in_sizes, int n_in,
                              void* d_out, int out_size, void* d_ws, size_t ws_size,
                              hipStream_t stream) {
    const float* poses    = (const float*)d_in[0];
    const float* wpts     = (const float*)d_in[1];
    const float* boundary = (const float*)d_in[2];
    const float* bnorm    = (const float*)d_in[3];
    float* out = (float*)d_out;

    u64* partial = (u64*)((char*)d_ws + PART_OFF);

    k_nn<<<NQG * BPQ, 256, 0, stream>>>(poses, wpts, boundary, partial, out);
    k_epilogue<<<NQ / EPI_T, EPI_T, 0, stream>>>(
        poses, wpts, boundary, bnorm, partial, out);
}

// Round 6
// 77.829 us; speedup vs baseline: 1.0090x; 1.0090x over previous
//
#include <hip/hip_runtime.h>
#include <math.h>
#include <float.h>

#define B_ 64
#define T_ 100
#define N_ 20000
#define NQ (B_ * T_)              // 6400 queries
#define QG 256                    // queries per group = one block (4 per lane)
#define NQG (NQ / QG)             // 25 query groups
#define PTB 800                   // points per block (4 waves x 200)
#define PPB (PTB / 2)             // 400 point-pairs per block
#define BPQ (N_ / PTB)            // 25 point-slices = blocks per query group
#define DGPW 25                   // double-groups (8 points) per wave
#define EPI_T 64                  // k_epilogue block size (grid 100)

typedef float f2 __attribute__((ext_vector_type(2)));
typedef float f4 __attribute__((ext_vector_type(4)));
typedef unsigned long long u64;

// ws layout: u64 partial[BPQ][NQ]  (25 * 6400 * 8 = 1.28 MB)
// Every slot is written by its owning block -> no init pass, no atomics.
#define PART_OFF 0

// Map f32 -> u32 preserving < order for all finite values (incl. negatives).
__device__ __forceinline__ unsigned int f32_sortable(float f) {
    unsigned int u = __float_as_uint(f);
    return ((int)u >= 0) ? (u | 0x80000000u) : ~u;
}

// e = p2 - 2 q.g for a point-PAIR, FMA nesting identical to the verified
// kernels: fma(mx, qx, fma(my, qy, fma(mz, qz, p2)))
__device__ __forceinline__ f2 edist2(f4 A, f4 Bv, f2 vx, f2 vy, f2 vz) {
    f2 mx = { A.x,  A.y  }, my = { A.z,  A.w  };
    f2 mz = { Bv.x, Bv.y }, p2 = { Bv.z, Bv.w };
    return __builtin_elementwise_fma(mx, vx,
           __builtin_elementwise_fma(my, vy,
           __builtin_elementwise_fma(mz, vz, p2)));
}

// ---------------------------------------------------------------------------
// Kernel 1: NN. Block = (query-group of 256, point-slice of 800).
// Rigid transforms preserve distance, so the search runs in the global
// frame: q = R w + t, e = |g|^2 - 2 q.g (argmin-equivalent to |q-g|^2).
// Query sharing: each THREAD computes one query (bit-identical expression),
// publishes via SoA LDS; each LANE then owns 4 queries as hoisted splats.
// Each WAVE covers all 256 queries x its 200-point sub-slice via uniform
// (broadcast, conflict-free) LDS reads; argmin tracked per 8-point
// double-group (best measured balance of bookkeeping vs register
// pressure: 20-point groups regressed via occupancy loss), resolved
// exactly afterwards with identical FMA math + lowest-index tie-break.
// Per block: 4 waves' keys min-reduce through LDS, one u64 per query to
// partial[slice][query]. No atomics, no init kernel.
// ---------------------------------------------------------------------------
__global__ __launch_bounds__(256, 4) void k_nn(
    const float* __restrict__ poses,      // [B,4,4]
    const float* __restrict__ wpts,       // [B,T,3]
    const float* __restrict__ boundary,   // [4,N]
    u64* __restrict__ partial,            // [BPQ][NQ]
    float* __restrict__ out)
{
    __shared__ f4 sh[PPB][2];             // pair-packed points, 12.8 KB
    __shared__ float qsh[3][QG];          // SoA queries, 3 KB
    __shared__ u64 red[4 * 256];          // cross-wave key reduce, 8 KB

    const int bx   = blockIdx.x;
    const int qg   = bx / BPQ;
    const int bsl  = bx - qg * BPQ;
    const int tid  = threadIdx.x;
    const int lane = tid & 63;
    const int wv   = tid >> 6;
    const int pbase = bsl * PTB;

    // out is consumed by k_epilogue (next dispatch) via atomicAdd; zero here.
    if (bx == 0 && tid == 0) out[0] = 0.0f;

    // ---- stage slice: (-2g, |g|^2) pair-packed (identical arithmetic) ----
    for (int pp = tid; pp < PPB; pp += 256) {
        const int n0 = pbase + 2 * pp;
        const f2 xx = *(const f2*)&boundary[n0];
        const f2 yy = *(const f2*)&boundary[N_ + n0];
        const f2 zz = *(const f2*)&boundary[2 * N_ + n0];
        const float x0 = xx.x, x1 = xx.y;
        const float y0 = yy.x, y1 = yy.y;
        const float z0 = zz.x, z1 = zz.y;
        f4 a = { -2.f * x0, -2.f * x1, -2.f * y0, -2.f * y1 };
        f4 b = { -2.f * z0, -2.f * z1,
                 x0 * x0 + y0 * y0 + z0 * z0,
                 x1 * x1 + y1 * y1 + z1 * z1 };
        sh[pp][0] = a;
        sh[pp][1] = b;
    }

    // ---- one query per thread: global waypoint q = R w + t -> LDS ----
    {
        const int i = qg * QG + tid;
        const int b = i / T_;
        const float* P = poses + b * 16;
        const float* W = wpts + i * 3;
        const float wx = W[0], wy = W[1], wz = W[2];
        qsh[0][tid] = P[0] * wx + P[1] * wy + P[2]  * wz + P[3];
        qsh[1][tid] = P[4] * wx + P[5] * wy + P[6]  * wz + P[7];
        qsh[2][tid] = P[8] * wx + P[9] * wy + P[10] * wz + P[11];
    }
    __syncthreads();

    // ---- 4 queries per lane, splats hoisted ----
    f2 vx[4], vy[4], vz[4];
#pragma unroll
    for (int s = 0; s < 4; ++s) {
        const int qi = s * 64 + lane;
        const float qxx = qsh[0][qi];
        const float qyy = qsh[1][qi];
        const float qzz = qsh[2][qi];
        vx[s] = (f2){ qxx, qxx };
        vy[s] = (f2){ qyy, qyy };
        vz[s] = (f2){ qzz, qzz };
    }

    const int prbase = wv * (PPB / 4);    // wave's pair base (wv*100)

    float best[4] = { FLT_MAX, FLT_MAX, FLT_MAX, FLT_MAX };
    int   bg[4]   = { 0, 0, 0, 0 };

#pragma unroll 5
    for (int g = 0; g < DGPW; ++g) {
        const int pr = prbase + 4 * g;
        const f4 A0 = sh[pr][0],     B0 = sh[pr][1];
        const f4 A1 = sh[pr + 1][0], B1 = sh[pr + 1][1];
        const f4 A2 = sh[pr + 2][0], B2 = sh[pr + 2][1];
        const f4 A3 = sh[pr + 3][0], B3 = sh[pr + 3][1];
#pragma unroll
        for (int s = 0; s < 4; ++s) {
            const f2 e01 = edist2(A0, B0, vx[s], vy[s], vz[s]);
            const f2 e23 = edist2(A1, B1, vx[s], vy[s], vz[s]);
            const f2 e45 = edist2(A2, B2, vx[s], vy[s], vz[s]);
            const f2 e67 = edist2(A3, B3, vx[s], vy[s], vz[s]);
            const f2 m0 = __builtin_elementwise_min(e01, e23);
            const f2 m1 = __builtin_elementwise_min(e45, e67);
            const f2 m  = __builtin_elementwise_min(m0, m1);
            const float sc = fminf(m.x, m.y);
            bg[s]   = (sc < best[s]) ? g : bg[s];
            best[s] = fminf(sc, best[s]);
        }
    }

    // ---- resolve exact index inside winning 8-group (identical FMA math) --
#pragma unroll
    for (int s = 0; s < 4; ++s) {
        const int pr = prbase + 4 * bg[s];
        const f4 A0 = sh[pr][0],     B0 = sh[pr][1];
        const f4 A1 = sh[pr + 1][0], B1 = sh[pr + 1][1];
        const f4 A2 = sh[pr + 2][0], B2 = sh[pr + 2][1];
        const f4 A3 = sh[pr + 3][0], B3 = sh[pr + 3][1];
        const f2 e01 = edist2(A0, B0, vx[s], vy[s], vz[s]);
        const f2 e23 = edist2(A1, B1, vx[s], vy[s], vz[s]);
        const f2 e45 = edist2(A2, B2, vx[s], vy[s], vz[s]);
        const f2 e67 = edist2(A3, B3, vx[s], vy[s], vz[s]);
        const int base_i = pbase + wv * 200 + 8 * bg[s];
        const int li = (e01.x == best[s]) ? base_i
                     : (e01.y == best[s]) ? base_i + 1
                     : (e23.x == best[s]) ? base_i + 2
                     : (e23.y == best[s]) ? base_i + 3
                     : (e45.x == best[s]) ? base_i + 4
                     : (e45.y == best[s]) ? base_i + 5
                     : (e67.x == best[s]) ? base_i + 6 : base_i + 7;
        red[wv * 256 + s * 64 + lane] =
            ((u64)f32_sortable(best[s]) << 32) | (unsigned)li;
    }
    __syncthreads();

    // ---- cross-wave min (4 slices of the block) -> one u64 per query ----
    {
        const u64 a = red[tid],       b = red[256 + tid];
        const u64 c = red[512 + tid], d = red[768 + tid];
        const u64 m0 = a < b ? a : b;
        const u64 m1 = c < d ? c : d;
        partial[bsl * NQ + qg * QG + tid] = m0 < m1 ? m0 : m1;
    }
}

// ---------------------------------------------------------------------------
// Kernel 2: per query, min over the 25 slice-partials (coalesced), unpack
// winning index, global-frame epilogue: dots = (q - g) . n (rotation-
// invariant == reference's local-frame dot), ExpRelu, block-reduce, atomicAdd.
// Grid 100 x 64 for wide CU coverage on the latency-sensitive gather.
// ---------------------------------------------------------------------------
__global__ __launch_bounds__(EPI_T) void k_epilogue(
    const float* __restrict__ poses,
    const float* __restrict__ wpts,
    const float* __restrict__ boundary,   // [4,N]
    const float* __restrict__ bnorm,      // [3,N]
    const u64* __restrict__ partial,
    float* __restrict__ out)
{
    const int tid = threadIdx.x;
    const int i = blockIdx.x * EPI_T + tid;   // grid = 100 -> i in [0,6400)

    u64 best = ~0ull;
#pragma unroll
    for (int sl = 0; sl < BPQ; ++sl) {
        const u64 k = partial[sl * NQ + i];
        best = k < best ? k : best;
    }
    const int bi = (int)(unsigned)(best & 0xFFFFFFFFull);

    const int b = i / T_;
    const float* P = poses + b * 16;
    const float* W = wpts + i * 3;
    const float wx = W[0], wy = W[1], wz = W[2];
    const float qx = P[0] * wx + P[1] * wy + P[2]  * wz + P[3];
    const float qy = P[4] * wx + P[5] * wy + P[6]  * wz + P[7];
    const float qz = P[8] * wx + P[9] * wy + P[10] * wz + P[11];

    const float gx = boundary[bi], gy = boundary[N_ + bi], gz = boundary[2 * N_ + bi];
    const float nx = bnorm[bi],    ny = bnorm[N_ + bi],    nz = bnorm[2 * N_ + bi];

    const float dots = (qx - gx) * nx + (qy - gy) * ny + (qz - gz) * nz;
    // ExpRelu: alpha=1, beta=0.5; pre-scaled for the final mean
    float val = (dots > 0.0f) ? (dots + 1.0f) : expf(0.5f * dots);
    val *= (1.0f / (float)NQ);

    __shared__ float redf[EPI_T];
    redf[tid] = val;
    __syncthreads();
#pragma unroll
    for (int s = EPI_T / 2; s > 0; s >>= 1) {
        if (tid < s) redf[tid] += redf[tid + s];
        __syncthreads();
    }
    if (tid == 0) atomicAdd(out, redf[0]);
}

extern "C" void kernel_launch(void* const* d_in, const int* in_sizes, int n_in,
                              void* d_out, int out_size, void* d_ws, size_t ws_size,
                              hipStream_t stream) {
    const float* poses    = (const float*)d_in[0];
    const float* wpts     = (const float*)d_in[1];
    const float* boundary = (const float*)d_in[2];
    const float* bnorm    = (const float*)d_in[3];
    float* out = (float*)d_out;

    u64* partial = (u64*)((char*)d_ws + PART_OFF);

    k_nn<<<NQG * BPQ, 256, 0, stream>>>(poses, wpts, boundary, partial, out);
    k_epilogue<<<NQ / EPI_T, EPI_T, 0, stream>>>(
        poses, wpts, boundary, bnorm, partial, out);
}